// Round 6
// baseline (920.010 us; speedup 1.0000x reference)
//
#include <hip/hip_runtime.h>
#include <math.h>

// GRU C=64, L=2, B=2048, SEQ=512, DEC=35. BT=8 rows/block, grid=256 (1 block/CU).
// 1024 threads = 16 waves. Gate columns padded to 4/channel (r,z,n,dummy) ->
// 256 cols; wave w owns cols [16w,16w+16) = channels 4w..4w+3 with ALL their
// gates, so each wave finishes its channels' GRU cell update in-wave (private
// LDS scratch, same-wave RAW ordered by lgkmcnt). 2 barriers per step:
//   R1: [flush h1(t-1)->stC] phaseA MFMA (stA) -> L0 cell -> h0: stC rows0-7 now,
//       stA rows8-15 DEFERRED                                    -> barrier
//   R2: [flush h0(t)->stA]   phaseC MFMA (stC) -> L1 cell -> h1: stC rows8-15
//       DEFERRED (decoder: also stA rows0-7 = x(t+1) now)        -> barrier
// Deferral rule: never store into a stage matrix that any wave's MFMA reads in
// the SAME barrier region (cross-wave race); R1 reads only stA, R2 only stC.
//
// Weights live in VGPR bf16 fragments all kernel. h stays f32 in owner-lane
// registers; bf16 only enters MFMA operands (round-4 numerics: absmax 1.8e-3).
// MFMA 16x16x32 bf16; A/B share one (group,elem)->k convention (k-perm cancels).
// C/D: col=lane&15, row=(lane>>4)*4+reg (HW-verified, learn_hip m89).

#define CCH  64
#define GG   192
#define SEQ  512
#define DECS 35
#define BT   8
#define NTH  1024
#define NW   16
#define SCR_STR 18                 // scratch row stride (f32): 2-way banks on C stores
#define STG_SH  (16 * 17 * 8)      // stage: [kgroup 0..15][row 0..16 pad][8 elems] bf16

typedef __attribute__((ext_vector_type(8))) short bf16x8;
typedef __attribute__((ext_vector_type(4))) float f32x4;

__device__ __forceinline__ short f2b(float f) {   // f32 -> bf16 RNE
  union { float f; unsigned u; } v; v.f = f;
  unsigned r = v.u + 0x7fffu + ((v.u >> 16) & 1u);
  return (short)(r >> 16);
}
__device__ __forceinline__ float sigf(float x) { return 1.0f / (1.0f + __expf(-x)); }
__device__ __forceinline__ float tanhfast(float x) {
  float t = __expf(-2.0f * fabsf(x));
  float r = (1.0f - t) / (1.0f + t);
  return copysignf(r, x);
}
__device__ __forceinline__ int stoff(int row, int k) {  // stage elem index
  return ((k >> 3) * 17 + row) * 8 + (k & 7);
}

extern "C" __global__ void __launch_bounds__(NTH, 1)
gru_fused(const float* __restrict__ pulse,   // [B,512,2]
          const float* __restrict__ d1w,     // [64,2]
          const float* __restrict__ d1b,     // [64]
          const float* __restrict__ d2w,     // [2,64]
          const float* __restrict__ d2b,     // [2]
          const float* __restrict__ Wih,     // [2,192,64]
          const float* __restrict__ Whh,     // [2,192,64]
          const float* __restrict__ bih,     // [2,192]
          const float* __restrict__ bhh,     // [2,192]
          const float* __restrict__ embed,   // [1,64]
          float* __restrict__ out)           // [B,35,2]
{
  __shared__ __align__(16) unsigned short stA[STG_SH];  // R1 operand (x | h0)
  __shared__ __align__(16) unsigned short stC[STG_SH];  // R2 operand (h0new | h1)
  __shared__ float scr[NW * 16 * SCR_STR];              // per-wave C scratch
  __shared__ float red[NW * 16];                        // dense2 partials [w][b*2+o]

  const int tid = threadIdx.x;
  const int wid = tid >> 6;       // wave = N-tile 0..15
  const int l   = tid & 63;
  const int lm  = l & 15;         // m/n lane index
  const int lg  = l >> 4;         // k-group
  const int bgb = blockIdx.x * BT;

  for (int i = tid; i < STG_SH; i += NTH) { stA[i] = 0; stC[i] = 0; }

  // ---- B-fragments (weights) -> VGPR bf16, held for whole kernel
  const float* Wih0 = Wih;
  const float* Whh0 = Whh;
  const float* Wih1 = Wih + GG * CCH;
  const float* Whh1 = Whh + GG * CCH;
  const int ncol = wid * 16 + lm;   // global padded column
  const int bch  = ncol >> 2;       // channel of this column
  const int bgt  = ncol & 3;        // gate 0..3 (3 = dummy zero column)
  bf16x8 bA[4], bC[4];
#pragma unroll
  for (int s = 0; s < 4; ++s) {
#pragma unroll
    for (int e = 0; e < 8; ++e) {
      int kk = 32 * s + 8 * lg + e;
      float va = 0.f, vc = 0.f;
      if (bgt < 3) {
        int row = bgt * CCH + bch;
        va = (kk < 64) ? Wih0[row * CCH + kk] : Whh0[row * CCH + kk - 64];
        vc = (kk < 64) ? Wih1[row * CCH + kk] : Whh1[row * CCH + kk - 64];
      }
      bA[s][e] = f2b(va);
      bC[s][e] = f2b(vc);
    }
  }

  // ---- owner-lane constants (lanes 0-31: lane = ob*4 + ocl)
  const int ob  = (l >> 2) & 7;     // batch row 0..7
  const int ocl = l & 3;            // local channel 0..3
  const int och = wid * 4 + ocl;    // channel 0..63
  float A0[3], A1[3], C0[3], bi0_[3], bh0_[3], bi1_[3], bh1_[3];
#pragma unroll
  for (int g = 0; g < 3; ++g) {
    int row = g * CCH + och;
    float a0 = 0.f, a1 = 0.f, cc = 0.f;
    for (int k = 0; k < CCH; ++k) {
      float wv = Wih0[row * CCH + k];
      a0 += wv * d1w[2 * k];
      a1 += wv * d1w[2 * k + 1];
      cc += wv * d1b[k];
    }
    A0[g] = a0; A1[g] = a1; C0[g] = cc + bih[row];   // exact f32 dense1 fold
    bi0_[g] = bih[row];      bh0_[g] = bhh[row];
    bi1_[g] = bih[GG + row]; bh1_[g] = bhh[GG + row];
  }
  const float w20 = d2w[och], w21 = d2w[CCH + och];
  const float ob0 = d2b[0], ob1 = d2b[1];
  float h0 = 0.f, h1 = 0.f;
  short hb0 = 0, hb1 = 0;          // deferred-store staging values

  float* ws = scr + wid * 16 * SCR_STR;   // this wave's private scratch
  __syncthreads();

  // ======================= encoder: 512 steps =======================
  for (int t = 0; t < SEQ; ++t) {
    // ---- R1: flush h1(t-1), gh0 MFMA (k-slices 2,3 only; x-block is zero), L0 cell
    if (l < 32) stC[stoff(8 + ob, 64 + och)] = hb1;   // deferred h1(t-1) -> R2 operand
    float2 pv = make_float2(0.f, 0.f);
    if (l < 32) pv = *(const float2*)(pulse + ((size_t)(bgb + ob) * SEQ + t) * 2);
    {
      f32x4 acc = {0.f, 0.f, 0.f, 0.f};
#pragma unroll
      for (int s = 2; s < 4; ++s) {
        bf16x8 af = *(const bf16x8*)&stA[((s * 4 + lg) * 17 + lm) * 8];
        acc = __builtin_amdgcn_mfma_f32_16x16x32_bf16(af, bA[s], acc, 0, 0, 0);
      }
#pragma unroll
      for (int r = 0; r < 4; ++r) ws[(lg * 4 + r) * SCR_STR + lm] = acc[r];
    }
    if (l < 32) {   // L0 cell: gi0 = exact fold, gh0 from own scratch rows 8-15
      float ghR = ws[(8 + ob) * SCR_STR + 4 * ocl + 0];
      float ghZ = ws[(8 + ob) * SCR_STR + 4 * ocl + 1];
      float ghN = ws[(8 + ob) * SCR_STR + 4 * ocl + 2];
      float giR = pv.x * A0[0] + pv.y * A1[0] + C0[0];
      float giZ = pv.x * A0[1] + pv.y * A1[1] + C0[1];
      float giN = pv.x * A0[2] + pv.y * A1[2] + C0[2];
      float r = sigf(giR + ghR + bh0_[0]);
      float z = sigf(giZ + ghZ + bh0_[1]);
      float nn = tanhfast(giN + r * (ghN + bh0_[2]));
      h0 = (1.f - z) * nn + z * h0;
      hb0 = f2b(h0);
      stC[stoff(ob, och)] = hb0;   // h0new -> R2 rows 0-7 (R2 reads after barrier)
    }                              // stA rows 8-15 write DEFERRED to R2
    __syncthreads();

    // ---- R2: flush h0(t), gi1+gh1 MFMA, L1 cell
    if (l < 32) stA[stoff(8 + ob, 64 + och)] = hb0;   // deferred h0(t) -> next R1
    {
      f32x4 acc = {0.f, 0.f, 0.f, 0.f};
#pragma unroll
      for (int s = 0; s < 4; ++s) {
        bf16x8 af = *(const bf16x8*)&stC[((s * 4 + lg) * 17 + lm) * 8];
        acc = __builtin_amdgcn_mfma_f32_16x16x32_bf16(af, bC[s], acc, 0, 0, 0);
      }
#pragma unroll
      for (int r = 0; r < 4; ++r) ws[(lg * 4 + r) * SCR_STR + lm] = acc[r];
    }
    if (l < 32) {   // L1 cell (h1 store deferred to next R1)
      float aR = ws[ob * SCR_STR + 4 * ocl + 0];
      float aZ = ws[ob * SCR_STR + 4 * ocl + 1];
      float aN = ws[ob * SCR_STR + 4 * ocl + 2];
      float hR = ws[(8 + ob) * SCR_STR + 4 * ocl + 0];
      float hZ = ws[(8 + ob) * SCR_STR + 4 * ocl + 1];
      float hN = ws[(8 + ob) * SCR_STR + 4 * ocl + 2];
      float r = sigf(aR + hR + bi1_[0] + bh1_[0]);
      float z = sigf(aZ + hZ + bi1_[1] + bh1_[1]);
      float nn = tanhfast(aN + bi1_[2] + r * (hN + bh1_[2]));
      h1 = (1.f - z) * nn + z * h1;
      hb1 = f2b(h1);
    }
    __syncthreads();
  }

  // ---- seed decoder input x = embed (stA rows 0-7 were still zero)
  if (l < 32) stA[stoff(ob, och)] = f2b(embed[och]);
  __syncthreads();

  // ======================= decoder: 35 steps =======================
  for (int d = 0; d < DECS; ++d) {
    // ---- R1: flush h1(d-1), gi0+gh0 MFMA (full K), L0 cell; lanes 32-47 of
    //      wave 0 reduce dense2 for step d-1
    if (l < 32) {
      stC[stoff(8 + ob, 64 + och)] = hb1;   // deferred h1(d-1) -> R2 operand
    } else if (wid == 0 && l < 48 && d > 0) {
      int i = l - 32, b = i >> 1, o = i & 1;
      float s = 0.f;
#pragma unroll
      for (int w = 0; w < NW; ++w) s += red[w * 16 + b * 2 + o];
      out[((size_t)(bgb + b) * DECS + (d - 1)) * 2 + o] = s + (o ? ob1 : ob0);
    }
    {
      f32x4 acc = {0.f, 0.f, 0.f, 0.f};
#pragma unroll
      for (int s = 0; s < 4; ++s) {
        bf16x8 af = *(const bf16x8*)&stA[((s * 4 + lg) * 17 + lm) * 8];
        acc = __builtin_amdgcn_mfma_f32_16x16x32_bf16(af, bA[s], acc, 0, 0, 0);
      }
#pragma unroll
      for (int r = 0; r < 4; ++r) ws[(lg * 4 + r) * SCR_STR + lm] = acc[r];
    }
    if (l < 32) {   // L0 cell, gi0 from MFMA rows 0-7
      float aR = ws[ob * SCR_STR + 4 * ocl + 0];
      float aZ = ws[ob * SCR_STR + 4 * ocl + 1];
      float aN = ws[ob * SCR_STR + 4 * ocl + 2];
      float hR = ws[(8 + ob) * SCR_STR + 4 * ocl + 0];
      float hZ = ws[(8 + ob) * SCR_STR + 4 * ocl + 1];
      float hN = ws[(8 + ob) * SCR_STR + 4 * ocl + 2];
      float r = sigf(aR + hR + bi0_[0] + bh0_[0]);
      float z = sigf(aZ + hZ + bi0_[1] + bh0_[1]);
      float nn = tanhfast(aN + bi0_[2] + r * (hN + bh0_[2]));
      h0 = (1.f - z) * nn + z * h0;
      hb0 = f2b(h0);
      stC[stoff(ob, och)] = hb0;   // h0new -> R2 rows 0-7
    }                              // stA rows 8-15 write DEFERRED to R2
    __syncthreads();

    // ---- R2: flush h0(d), gi1+gh1 MFMA, L1 cell + x-store + dense2 partial
    if (l < 32) stA[stoff(8 + ob, 64 + och)] = hb0;   // deferred h0(d) -> next R1
    {
      f32x4 acc = {0.f, 0.f, 0.f, 0.f};
#pragma unroll
      for (int s = 0; s < 4; ++s) {
        bf16x8 af = *(const bf16x8*)&stC[((s * 4 + lg) * 17 + lm) * 8];
        acc = __builtin_amdgcn_mfma_f32_16x16x32_bf16(af, bC[s], acc, 0, 0, 0);
      }
#pragma unroll
      for (int r = 0; r < 4; ++r) ws[(lg * 4 + r) * SCR_STR + lm] = acc[r];
    }
    if (l < 32) {
      float aR = ws[ob * SCR_STR + 4 * ocl + 0];
      float aZ = ws[ob * SCR_STR + 4 * ocl + 1];
      float aN = ws[ob * SCR_STR + 4 * ocl + 2];
      float hR = ws[(8 + ob) * SCR_STR + 4 * ocl + 0];
      float hZ = ws[(8 + ob) * SCR_STR + 4 * ocl + 1];
      float hN = ws[(8 + ob) * SCR_STR + 4 * ocl + 2];
      float r = sigf(aR + hR + bi1_[0] + bh1_[0]);
      float z = sigf(aZ + hZ + bi1_[1] + bh1_[1]);
      float nn = tanhfast(aN + bi1_[2] + r * (hN + bh1_[2]));
      h1 = (1.f - z) * nn + z * h1;
      hb1 = f2b(h1);                       // stC rows 8-15 DEFERRED to next R1
      stA[stoff(ob, och)] = hb1;           // x(d+1) -> R1 rows 0-7 (R1 reads after barrier)
      float p0 = h1 * w20, p1 = h1 * w21;  // dense2 partial over wave's 4 channels
      p0 += __shfl_xor(p0, 1); p0 += __shfl_xor(p0, 2);
      p1 += __shfl_xor(p1, 1); p1 += __shfl_xor(p1, 2);
      if (ocl == 0) {
        red[wid * 16 + ob * 2 + 0] = p0;
        red[wid * 16 + ob * 2 + 1] = p1;
      }
    }
    __syncthreads();
  }

  // ---- final output flush (d = 34)
  if (wid == 0 && l >= 32 && l < 48) {
    int i = l - 32, b = i >> 1, o = i & 1;
    float s = 0.f;
#pragma unroll
    for (int w = 0; w < NW; ++w) s += red[w * 16 + b * 2 + o];
    out[((size_t)(bgb + b) * DECS + (DECS - 1)) * 2 + o] = s + (o ? ob1 : ob0);
  }
}

extern "C" void kernel_launch(void* const* d_in, const int* in_sizes, int n_in,
                              void* d_out, int out_size, void* d_ws, size_t ws_size,
                              hipStream_t stream) {
  const float* pulse = (const float*)d_in[0];
  const float* d1w   = (const float*)d_in[1];
  const float* d1b   = (const float*)d_in[2];
  const float* d2w   = (const float*)d_in[3];
  const float* d2b   = (const float*)d_in[4];
  const float* Wih   = (const float*)d_in[5];
  const float* Whh   = (const float*)d_in[6];
  const float* bih   = (const float*)d_in[7];
  const float* bhh   = (const float*)d_in[8];
  const float* emb   = (const float*)d_in[9];
  float* out = (float*)d_out;

  int B = in_sizes[0] / (SEQ * 2);   // 2048
  gru_fused<<<B / BT, NTH, 0, stream>>>(pulse, d1w, d1b, d2w, d2b,
                                        Wih, Whh, bih, bhh, emb, out);
}

// Round 7
// 607.818 us; speedup vs baseline: 1.5136x; 1.5136x over previous
//
#include <hip/hip_runtime.h>
#include <math.h>

// GRU C=64, L=2, B=2048, SEQ=512, DEC=35. BT=8 rows/block, grid=256 (1 block/CU).
// 512 threads = 8 waves. Padded gate cols (r,z,n,dummy per channel) -> 256 cols;
// wave w owns cols [32w,32w+32) = 2 MFMA N-tiles, with column order within the
// wave cc=(g<<3)|ocl so cell lanes (ob*8+ocl) get FULL 64-lane utilization.
// A-fragments are shared across a wave's 2 tiles (B-frags live in VGPRs), so
// doubling tiles/wave adds no LDS reads. 2 barriers/step with the deferred-
// store discipline (R1 writes only stC / reads only stA; R2 the reverse):
//   R1: flush h1(t-1)->stC | MFMA(stA) -> in-wave L0 cell -> h0 -> stC rows0-7
//   R2: flush h0(t)->stA   | MFMA(stC) -> in-wave L1 cell (decoder: +x-store)
// Weights: VGPR bf16 frags all kernel. h stays f32 in owner-lane registers.
// MFMA 16x16x32 bf16; A/B share one (s,lg,e)->k map (HW k-perm cancels).
// C/D: col=lane&15, row=(lane>>4)*4+reg (HW-verified, learn_hip m89).

#define CCH  64
#define GG   192
#define SEQ  512
#define DECS 35
#define BT   8
#define NTH  512
#define NW   8
#define RSTR 20                    // scr col stride (f32), b128-aligned, ~2-way reads
#define STG_SH  (16 * 17 * 8)      // stage: [kgroup 0..15][row 0..16 pad][8] bf16

typedef __attribute__((ext_vector_type(8))) short bf16x8;
typedef __attribute__((ext_vector_type(4))) float f32x4;

__device__ __forceinline__ short f2b(float f) {   // f32 -> bf16 RNE
  union { float f; unsigned u; } v; v.f = f;
  unsigned r = v.u + 0x7fffu + ((v.u >> 16) & 1u);
  return (short)(r >> 16);
}
__device__ __forceinline__ float sigf(float x) { return 1.0f / (1.0f + __expf(-x)); }
__device__ __forceinline__ float tanhfast(float x) {
  float t = __expf(-2.0f * fabsf(x));
  float r = (1.0f - t) / (1.0f + t);
  return copysignf(r, x);
}
__device__ __forceinline__ int stoff(int row, int k) {  // stage elem index
  return ((k >> 3) * 17 + row) * 8 + (k & 7);
}

extern "C" __global__ void __launch_bounds__(NTH, 2)
gru_fused2(const float* __restrict__ pulse,   // [B,512,2]
           const float* __restrict__ d1w,     // [64,2]
           const float* __restrict__ d1b,     // [64]
           const float* __restrict__ d2w,     // [2,64]
           const float* __restrict__ d2b,     // [2]
           const float* __restrict__ Wih,     // [2,192,64]
           const float* __restrict__ Whh,     // [2,192,64]
           const float* __restrict__ bih,     // [2,192]
           const float* __restrict__ bhh,     // [2,192]
           const float* __restrict__ embed,   // [1,64]
           float* __restrict__ out)           // [B,35,2]
{
  __shared__ __align__(16) unsigned short stA[STG_SH];  // R1 operand (x | h0)
  __shared__ __align__(16) unsigned short stC[STG_SH];  // R2 operand (h0new | h1)
  __shared__ __align__(16) float scr[NW * 32 * RSTR];   // per-wave C scratch [col][row]
  __shared__ float red[NW * 16];                        // dense2 partials [w][b*2+o]

  const int tid = threadIdx.x;
  const int wid = tid >> 6;       // wave 0..7
  const int l   = tid & 63;
  const int lm  = l & 15;         // MFMA m/n lane index
  const int lg  = l >> 4;         // MFMA k-group
  const int ob  = l >> 3;         // cell: batch row 0..7
  const int ocl = l & 7;          // cell: local channel 0..7
  const int och = wid * 8 + ocl;  // cell: global channel
  const int bgb = blockIdx.x * BT;

  for (int i = tid; i < STG_SH; i += NTH) { stA[i] = 0; stC[i] = 0; }

  // ---- B-fragments (weights) -> VGPR bf16, held for whole kernel.
  // Wave's local col cc = t*16+lm; gate g = cc>>3 (3 = dummy), channel wid*8+(cc&7).
  const float* Wih0 = Wih;
  const float* Whh0 = Whh;
  const float* Wih1 = Wih + GG * CCH;
  const float* Whh1 = Whh + GG * CCH;
  bf16x8 bA[2][4], bC[2][4];
#pragma unroll
  for (int t = 0; t < 2; ++t) {
    const int cc = t * 16 + lm;
    const int g  = cc >> 3;
    const int ch = wid * 8 + (cc & 7);
#pragma unroll
    for (int s = 0; s < 4; ++s) {
#pragma unroll
      for (int e = 0; e < 8; ++e) {
        int kk = 32 * s + 8 * lg + e;
        float va = 0.f, vc = 0.f;
        if (g < 3) {
          int row = g * CCH + ch;
          va = (kk < 64) ? Wih0[row * CCH + kk] : Whh0[row * CCH + kk - 64];
          vc = (kk < 64) ? Wih1[row * CCH + kk] : Whh1[row * CCH + kk - 64];
        }
        bA[t][s][e] = f2b(va);
        bC[t][s][e] = f2b(vc);
      }
    }
  }

  // ---- per-lane cell constants (channel och; all 64 lanes valid)
  float A0[3], A1[3], C0[3], bi0_[3], bh0_[3], bi1_[3], bh1_[3];
#pragma unroll
  for (int g = 0; g < 3; ++g) {
    int row = g * CCH + och;
    float a0 = 0.f, a1 = 0.f, cc = 0.f;
    for (int k = 0; k < CCH; ++k) {
      float wv = Wih0[row * CCH + k];
      a0 += wv * d1w[2 * k];
      a1 += wv * d1w[2 * k + 1];
      cc += wv * d1b[k];
    }
    A0[g] = a0; A1[g] = a1; C0[g] = cc + bih[row];   // exact f32 dense1 fold
    bi0_[g] = bih[row];      bh0_[g] = bhh[row];
    bi1_[g] = bih[GG + row]; bh1_[g] = bhh[GG + row];
  }
  const float w20 = d2w[och], w21 = d2w[CCH + och];
  const float o_b0 = d2b[0], o_b1 = d2b[1];
  float h0 = 0.f, h1 = 0.f;
  short hb0 = 0, hb1 = 0;          // deferred-store staging values

  float* ws = scr + wid * 32 * RSTR;   // this wave's scratch [32 cols][20]
  __syncthreads();

  // ======================= encoder: 512 steps =======================
  for (int t = 0; t < SEQ; ++t) {
    // ---- R1: flush h1(t-1)->stC; gh0 MFMA (k-slices 2,3; x-block is zero); L0 cell
    stC[stoff(8 + ob, 64 + och)] = hb1;
    float2 pv = *(const float2*)(pulse + ((size_t)(bgb + ob) * SEQ + t) * 2);
    {
      f32x4 a0 = {0.f, 0.f, 0.f, 0.f}, a1 = {0.f, 0.f, 0.f, 0.f};
#pragma unroll
      for (int s = 2; s < 4; ++s) {
        bf16x8 af = *(const bf16x8*)&stA[((s * 4 + lg) * 17 + lm) * 8];
        a0 = __builtin_amdgcn_mfma_f32_16x16x32_bf16(af, bA[0][s], a0, 0, 0, 0);
        a1 = __builtin_amdgcn_mfma_f32_16x16x32_bf16(af, bA[1][s], a1, 0, 0, 0);
      }
      *(f32x4*)(ws + (0 * 16 + lm) * RSTR + lg * 4) = a0;
      *(f32x4*)(ws + (1 * 16 + lm) * RSTR + lg * 4) = a1;
    }
    {   // L0 cell: gi0 = exact rank-2 fold; gh0 from scratch rows 8-15
      float ghR = ws[(0 * 8 + ocl) * RSTR + 8 + ob];
      float ghZ = ws[(1 * 8 + ocl) * RSTR + 8 + ob];
      float ghN = ws[(2 * 8 + ocl) * RSTR + 8 + ob];
      float giR = pv.x * A0[0] + pv.y * A1[0] + C0[0];
      float giZ = pv.x * A0[1] + pv.y * A1[1] + C0[1];
      float giN = pv.x * A0[2] + pv.y * A1[2] + C0[2];
      float r = sigf(giR + ghR + bh0_[0]);
      float z = sigf(giZ + ghZ + bh0_[1]);
      float nn = tanhfast(giN + r * (ghN + bh0_[2]));
      h0 = (1.f - z) * nn + z * h0;
      hb0 = f2b(h0);
      stC[stoff(ob, och)] = hb0;       // h0new -> R2 rows 0-7
    }                                  // stA rows 8-15 DEFERRED to R2
    __syncthreads();

    // ---- R2: flush h0(t)->stA; gi1+gh1 MFMA; L1 cell
    stA[stoff(8 + ob, 64 + och)] = hb0;
    {
      f32x4 a0 = {0.f, 0.f, 0.f, 0.f}, a1 = {0.f, 0.f, 0.f, 0.f};
#pragma unroll
      for (int s = 0; s < 4; ++s) {
        bf16x8 af = *(const bf16x8*)&stC[((s * 4 + lg) * 17 + lm) * 8];
        a0 = __builtin_amdgcn_mfma_f32_16x16x32_bf16(af, bC[0][s], a0, 0, 0, 0);
        a1 = __builtin_amdgcn_mfma_f32_16x16x32_bf16(af, bC[1][s], a1, 0, 0, 0);
      }
      *(f32x4*)(ws + (0 * 16 + lm) * RSTR + lg * 4) = a0;
      *(f32x4*)(ws + (1 * 16 + lm) * RSTR + lg * 4) = a1;
    }
    {   // L1 cell (h1 stage-store deferred to next R1)
      float aR = ws[(0 * 8 + ocl) * RSTR + ob];
      float aZ = ws[(1 * 8 + ocl) * RSTR + ob];
      float aN = ws[(2 * 8 + ocl) * RSTR + ob];
      float hR = ws[(0 * 8 + ocl) * RSTR + 8 + ob];
      float hZ = ws[(1 * 8 + ocl) * RSTR + 8 + ob];
      float hN = ws[(2 * 8 + ocl) * RSTR + 8 + ob];
      float r = sigf(aR + hR + bi1_[0] + bh1_[0]);
      float z = sigf(aZ + hZ + bi1_[1] + bh1_[1]);
      float nn = tanhfast(aN + bi1_[2] + r * (hN + bh1_[2]));
      h1 = (1.f - z) * nn + z * h1;
      hb1 = f2b(h1);
    }
    __syncthreads();
  }

  // ---- seed decoder input x = embed (stA rows 0-7 were still zero)
  stA[stoff(ob, och)] = f2b(embed[och]);
  __syncthreads();

  // ======================= decoder: 35 steps =======================
  for (int d = 0; d < DECS; ++d) {
    // ---- R1: flush h1(d-1)->stC; wave0 reduces dense2(d-1); gi0+gh0 MFMA; L0 cell
    stC[stoff(8 + ob, 64 + och)] = hb1;
    if (wid == 0 && l < 16 && d > 0) {
      int b = l >> 1, o = l & 1;
      float s = 0.f;
#pragma unroll
      for (int w = 0; w < NW; ++w) s += red[w * 16 + b * 2 + o];
      out[((size_t)(bgb + b) * DECS + (d - 1)) * 2 + o] = s + (o ? o_b1 : o_b0);
    }
    {
      f32x4 a0 = {0.f, 0.f, 0.f, 0.f}, a1 = {0.f, 0.f, 0.f, 0.f};
#pragma unroll
      for (int s = 0; s < 4; ++s) {
        bf16x8 af = *(const bf16x8*)&stA[((s * 4 + lg) * 17 + lm) * 8];
        a0 = __builtin_amdgcn_mfma_f32_16x16x32_bf16(af, bA[0][s], a0, 0, 0, 0);
        a1 = __builtin_amdgcn_mfma_f32_16x16x32_bf16(af, bA[1][s], a1, 0, 0, 0);
      }
      *(f32x4*)(ws + (0 * 16 + lm) * RSTR + lg * 4) = a0;
      *(f32x4*)(ws + (1 * 16 + lm) * RSTR + lg * 4) = a1;
    }
    {   // L0 cell: gi0 from MFMA rows 0-7, gh0 rows 8-15
      float aR = ws[(0 * 8 + ocl) * RSTR + ob];
      float aZ = ws[(1 * 8 + ocl) * RSTR + ob];
      float aN = ws[(2 * 8 + ocl) * RSTR + ob];
      float hR = ws[(0 * 8 + ocl) * RSTR + 8 + ob];
      float hZ = ws[(1 * 8 + ocl) * RSTR + 8 + ob];
      float hN = ws[(2 * 8 + ocl) * RSTR + 8 + ob];
      float r = sigf(aR + hR + bi0_[0] + bh0_[0]);
      float z = sigf(aZ + hZ + bi0_[1] + bh0_[1]);
      float nn = tanhfast(aN + bi0_[2] + r * (hN + bh0_[2]));
      h0 = (1.f - z) * nn + z * h0;
      hb0 = f2b(h0);
      stC[stoff(ob, och)] = hb0;       // h0new -> R2 rows 0-7
    }                                  // stA rows 8-15 DEFERRED to R2
    __syncthreads();

    // ---- R2: flush h0(d)->stA; gi1+gh1 MFMA; L1 cell + x-store + dense2 partial
    stA[stoff(8 + ob, 64 + och)] = hb0;
    {
      f32x4 a0 = {0.f, 0.f, 0.f, 0.f}, a1 = {0.f, 0.f, 0.f, 0.f};
#pragma unroll
      for (int s = 0; s < 4; ++s) {
        bf16x8 af = *(const bf16x8*)&stC[((s * 4 + lg) * 17 + lm) * 8];
        a0 = __builtin_amdgcn_mfma_f32_16x16x32_bf16(af, bC[0][s], a0, 0, 0, 0);
        a1 = __builtin_amdgcn_mfma_f32_16x16x32_bf16(af, bC[1][s], a1, 0, 0, 0);
      }
      *(f32x4*)(ws + (0 * 16 + lm) * RSTR + lg * 4) = a0;
      *(f32x4*)(ws + (1 * 16 + lm) * RSTR + lg * 4) = a1;
    }
    {
      float aR = ws[(0 * 8 + ocl) * RSTR + ob];
      float aZ = ws[(1 * 8 + ocl) * RSTR + ob];
      float aN = ws[(2 * 8 + ocl) * RSTR + ob];
      float hR = ws[(0 * 8 + ocl) * RSTR + 8 + ob];
      float hZ = ws[(1 * 8 + ocl) * RSTR + 8 + ob];
      float hN = ws[(2 * 8 + ocl) * RSTR + 8 + ob];
      float r = sigf(aR + hR + bi1_[0] + bh1_[0]);
      float z = sigf(aZ + hZ + bi1_[1] + bh1_[1]);
      float nn = tanhfast(aN + bi1_[2] + r * (hN + bh1_[2]));
      h1 = (1.f - z) * nn + z * h1;
      hb1 = f2b(h1);                    // stC rows 8-15 DEFERRED to next R1
      stA[stoff(ob, och)] = hb1;        // x(d+1) -> R1 rows 0-7
      float p0 = h1 * w20, p1 = h1 * w21;   // dense2 partial over wave's 8 channels
      p0 += __shfl_xor(p0, 1); p0 += __shfl_xor(p0, 2); p0 += __shfl_xor(p0, 4);
      p1 += __shfl_xor(p1, 1); p1 += __shfl_xor(p1, 2); p1 += __shfl_xor(p1, 4);
      if (ocl == 0) {
        red[wid * 16 + ob * 2 + 0] = p0;
        red[wid * 16 + ob * 2 + 1] = p1;
      }
    }
    __syncthreads();
  }

  // ---- final output flush (d = 34)
  if (wid == 0 && l < 16) {
    int b = l >> 1, o = l & 1;
    float s = 0.f;
#pragma unroll
    for (int w = 0; w < NW; ++w) s += red[w * 16 + b * 2 + o];
    out[((size_t)(bgb + b) * DECS + (DECS - 1)) * 2 + o] = s + (o ? o_b1 : o_b0);
  }
}

extern "C" void kernel_launch(void* const* d_in, const int* in_sizes, int n_in,
                              void* d_out, int out_size, void* d_ws, size_t ws_size,
                              hipStream_t stream) {
  const float* pulse = (const float*)d_in[0];
  const float* d1w   = (const float*)d_in[1];
  const float* d1b   = (const float*)d_in[2];
  const float* d2w   = (const float*)d_in[3];
  const float* d2b   = (const float*)d_in[4];
  const float* Wih   = (const float*)d_in[5];
  const float* Whh   = (const float*)d_in[6];
  const float* bih   = (const float*)d_in[7];
  const float* bhh   = (const float*)d_in[8];
  const float* emb   = (const float*)d_in[9];
  float* out = (float*)d_out;

  int B = in_sizes[0] / (SEQ * 2);   // 2048
  gru_fused2<<<B / BT, NTH, 0, stream>>>(pulse, d1w, d1b, d2w, d2b,
                                         Wih, Whh, bih, bhh, emb, out);
}

// Round 8
// 576.972 us; speedup vs baseline: 1.5946x; 1.0535x over previous
//
#include <hip/hip_runtime.h>
#include <math.h>

// GRU C=64, L=2, B=2048, SEQ=512, DEC=35. BT=8 rows/block, grid=256 (1/CU).
// 512 threads = 8 waves.
//
// LANE-LOCAL CELL DESIGN:
//  - One matmul form per phase: G[gate][b] = [Wih|Whh](k=128) . [x_b ; h_b]
//    (weights are the MFMA A operand, staged activations the B operand).
//    r,z rows use full-K concat -> MFMA emits gi+gh directly. n is split into
//    two rows: n_i=[Wih_n|0], n_h=[0|Whh_n] (needed separately for r*gh_n).
//  - Padded gate rows per channel: {r,z,ni,nh}. Wave w owns channels
//    8w..8w+7 as 2 tiles of 16 rows, rows ordered [ch0:r,z,ni,nh, ch1:...].
//    C/D layout (col=lane&15, row=(lane>>4)*4+reg; HW-verified m89) then puts
//    ALL FOUR gates of cell (b=col, ch=quad) into ONE lane's 4 acc regs:
//    reg0=r(sum), reg1=z(sum), reg2=gi_n, reg3=gh_n. Cell is pure-register.
//  - Stage cols 8-15 mirror cols 0-7 so lanes lm>=8 own tile-1 cells: every
//    lane owns exactly one (b, ch) cell. No scratch LDS, no shfl in cell.
//  - 2 barriers/step, deferred-store discipline: R1 reads stA / writes stC;
//    R2 reads stC / writes stA. h0->stC(now)+stA(deferred to R2);
//    h1->stC(deferred to next R1); decoder x=h1->stA(now, in R2).
//  - Encoder phase A skips k<64 slices (x=0); exact f32 rank-2 dense1 fold
//    supplies gi0 (incl bih). A/B share one (s,lg,e)->k map (HW k-perm cancels).

#define CCH  64
#define GG   192
#define SEQ  512
#define DECS 35
#define BT   8
#define NTH  512
#define NW   8
#define STG_SH (16 * 17 * 8)   // [kgroup 0..15][col 0..16 pad][8 elems] bf16

typedef __attribute__((ext_vector_type(8))) short bf16x8;
typedef __attribute__((ext_vector_type(4))) float f32x4;

__device__ __forceinline__ short f2b(float f) {   // f32 -> bf16 RNE
  union { float f; unsigned u; } v; v.f = f;
  unsigned r = v.u + 0x7fffu + ((v.u >> 16) & 1u);
  return (short)(r >> 16);
}
__device__ __forceinline__ float sigf(float x) { return 1.0f / (1.0f + __expf(-x)); }
__device__ __forceinline__ float tanhfast(float x) {
  float t = __expf(-2.0f * fabsf(x));
  float r = (1.0f - t) / (1.0f + t);
  return copysignf(r, x);
}
__device__ __forceinline__ int stoff(int col, int k) {  // stage elem index
  return ((k >> 3) * 17 + col) * 8 + (k & 7);
}

extern "C" __global__ void __launch_bounds__(NTH, 2)
gru_lane(const float* __restrict__ pulse,   // [B,512,2]
         const float* __restrict__ d1w,     // [64,2]
         const float* __restrict__ d1b,     // [64]
         const float* __restrict__ d2w,     // [2,64]
         const float* __restrict__ d2b,     // [2]
         const float* __restrict__ Wih,     // [2,192,64]
         const float* __restrict__ Whh,     // [2,192,64]
         const float* __restrict__ bih,     // [2,192]
         const float* __restrict__ bhh,     // [2,192]
         const float* __restrict__ embed,   // [1,64]
         float* __restrict__ out)           // [B,35,2]
{
  __shared__ __align__(16) unsigned short stA[STG_SH];  // R1 operand [x | h0]
  __shared__ __align__(16) unsigned short stC[STG_SH];  // R2 operand [h0new | h1]
  __shared__ float red[NW * 16];                        // dense2 partials

  const int tid = threadIdx.x;
  const int wid = tid >> 6;       // wave 0..7
  const int l   = tid & 63;
  const int lm  = l & 15;         // MFMA col (slot) / weight-row index
  const int lg  = l >> 4;         // k-group / acc quad
  const int b   = lm & 7;         // cell: batch row
  const int ch  = wid * 8 + ((lm >> 3) << 2) + lg;   // cell: global channel
  const int bgb = blockIdx.x * BT;

  for (int i = tid; i < STG_SH; i += NTH) { stA[i] = 0; stC[i] = 0; }

  // ---- weight A-fragments (held in VGPR all kernel)
  const float* Wih0 = Wih;
  const float* Whh0 = Whh;
  const float* Wih1 = Wih + GG * CCH;
  const float* Whh1 = Whh + GG * CCH;
  const int sub = lm & 3;          // 0=r 1=z 2=ni 3=nh
  bf16x8 bA[2][4], bC[2][4];
#pragma unroll
  for (int t = 0; t < 2; ++t) {
    const int wch = wid * 8 + t * 4 + (lm >> 2);   // channel of this weight row
    const int rr  = (sub == 0 ? wch : (sub == 1 ? 64 + wch : 128 + wch));
#pragma unroll
    for (int s = 0; s < 4; ++s) {
#pragma unroll
      for (int e = 0; e < 8; ++e) {
        int kk = 32 * s + 8 * lg + e;
        float va, vc;
        if (sub == 2) {        // n_i = [Wih_n | 0]
          va = kk < 64 ? Wih0[rr * CCH + kk] : 0.f;
          vc = kk < 64 ? Wih1[rr * CCH + kk] : 0.f;
        } else if (sub == 3) { // n_h = [0 | Whh_n]
          va = kk < 64 ? 0.f : Whh0[rr * CCH + kk - 64];
          vc = kk < 64 ? 0.f : Whh1[rr * CCH + kk - 64];
        } else {               // r,z = [Wih | Whh] full-K concat
          va = kk < 64 ? Wih0[rr * CCH + kk] : Whh0[rr * CCH + kk - 64];
          vc = kk < 64 ? Wih1[rr * CCH + kk] : Whh1[rr * CCH + kk - 64];
        }
        bA[t][s][e] = f2b(va);
        bC[t][s][e] = f2b(vc);
      }
    }
  }

  // ---- per-lane cell constants for channel ch
  float A0f[3], A1f[3], C0f[3];
#pragma unroll
  for (int g = 0; g < 3; ++g) {    // exact f32 dense1 fold (incl bih)
    int row = g * CCH + ch;
    float a0 = 0.f, a1 = 0.f, cc = 0.f;
    for (int k = 0; k < CCH; ++k) {
      float wv = Wih0[row * CCH + k];
      a0 += wv * d1w[2 * k];
      a1 += wv * d1w[2 * k + 1];
      cc += wv * d1b[k];
    }
    A0f[g] = a0; A1f[g] = a1; C0f[g] = cc + bih[row];
  }
  const float bh0r = bhh[ch], bh0z = bhh[64 + ch], bh0n = bhh[128 + ch];
  const float b0r = bih[ch] + bh0r, b0z = bih[64 + ch] + bh0z;
  const float bi0n = bih[128 + ch];
  const float b1r = bih[GG + ch] + bhh[GG + ch];
  const float b1z = bih[GG + 64 + ch] + bhh[GG + 64 + ch];
  const float bi1n = bih[GG + 128 + ch], bh1n = bhh[GG + 128 + ch];
  const float w2a = d2w[ch], w2b = d2w[CCH + ch];
  const float d2b0 = d2b[0], d2b1 = d2b[1];
  float h0 = 0.f, h1 = 0.f;
  short hb0 = 0, hb1 = 0;

  const float* prow = pulse + (size_t)(bgb + b) * SEQ * 2;
  __syncthreads();

  // ======================= encoder: 512 steps =======================
  for (int t = 0; t < SEQ; ++t) {
    // ---- R1: flush h1(t-1)->stC; gh0 MFMA (k-slices 2,3); lane-local L0 cell
    stC[stoff(b, 64 + ch)] = hb1;
    stC[stoff(8 + b, 64 + ch)] = hb1;
    float2 pv = *(const float2*)(prow + 2 * t);
    f32x4 a0 = {0.f, 0.f, 0.f, 0.f}, a1 = {0.f, 0.f, 0.f, 0.f};
#pragma unroll
    for (int s = 2; s < 4; ++s) {
      bf16x8 af = *(const bf16x8*)&stA[((s * 4 + lg) * 17 + lm) * 8];
      a0 = __builtin_amdgcn_mfma_f32_16x16x32_bf16(bA[0][s], af, a0, 0, 0, 0);
      a1 = __builtin_amdgcn_mfma_f32_16x16x32_bf16(bA[1][s], af, a1, 0, 0, 0);
    }
    {
      f32x4 g = (lm < 8) ? a0 : a1;   // this lane's cell gates
      float fr = pv.x * A0f[0] + pv.y * A1f[0] + C0f[0];
      float fz = pv.x * A0f[1] + pv.y * A1f[1] + C0f[1];
      float fn = pv.x * A0f[2] + pv.y * A1f[2] + C0f[2];
      float r = sigf(fr + g[0] + bh0r);
      float z = sigf(fz + g[1] + bh0z);
      float nn = tanhfast(fn + r * (g[3] + bh0n));
      h0 = (1.f - z) * nn + z * h0;
      hb0 = f2b(h0);
      stC[stoff(b, ch)] = hb0;        // h0new -> R2 x-part (both mirrors)
      stC[stoff(8 + b, ch)] = hb0;
    }                                 // stA k>=64 write DEFERRED to R2
    __syncthreads();

    // ---- R2: flush h0(t)->stA; gi1+gh1 MFMA; lane-local L1 cell
    stA[stoff(b, 64 + ch)] = hb0;
    stA[stoff(8 + b, 64 + ch)] = hb0;
    f32x4 c0 = {0.f, 0.f, 0.f, 0.f}, c1 = {0.f, 0.f, 0.f, 0.f};
#pragma unroll
    for (int s = 0; s < 4; ++s) {
      bf16x8 cf = *(const bf16x8*)&stC[((s * 4 + lg) * 17 + lm) * 8];
      c0 = __builtin_amdgcn_mfma_f32_16x16x32_bf16(bC[0][s], cf, c0, 0, 0, 0);
      c1 = __builtin_amdgcn_mfma_f32_16x16x32_bf16(bC[1][s], cf, c1, 0, 0, 0);
    }
    {
      f32x4 g = (lm < 8) ? c0 : c1;
      float r = sigf(g[0] + b1r);
      float z = sigf(g[1] + b1z);
      float nn = tanhfast(g[2] + bi1n + r * (g[3] + bh1n));
      h1 = (1.f - z) * nn + z * h1;
      hb1 = f2b(h1);                  // stC k>=64 DEFERRED to next R1
    }
    __syncthreads();
  }

  // ---- seed decoder input x = embed
  {
    short eb = f2b(embed[ch]);
    stA[stoff(b, ch)] = eb;
    stA[stoff(8 + b, ch)] = eb;
  }
  __syncthreads();

  // ======================= decoder: 35 steps =======================
  for (int d = 0; d < DECS; ++d) {
    // ---- R1: flush h1(d-1)->stC; wave0 reduces dense2(d-1); full-K MFMA; L0 cell
    stC[stoff(b, 64 + ch)] = hb1;
    stC[stoff(8 + b, 64 + ch)] = hb1;
    if (wid == 0 && l < 16 && d > 0) {
      int bb = l >> 1, o = l & 1;
      float s = 0.f;
#pragma unroll
      for (int w = 0; w < NW; ++w) s += red[w * 16 + bb * 2 + o];
      out[((size_t)(bgb + bb) * DECS + (d - 1)) * 2 + o] = s + (o ? d2b1 : d2b0);
    }
    f32x4 a0 = {0.f, 0.f, 0.f, 0.f}, a1 = {0.f, 0.f, 0.f, 0.f};
#pragma unroll
    for (int s = 0; s < 4; ++s) {
      bf16x8 af = *(const bf16x8*)&stA[((s * 4 + lg) * 17 + lm) * 8];
      a0 = __builtin_amdgcn_mfma_f32_16x16x32_bf16(bA[0][s], af, a0, 0, 0, 0);
      a1 = __builtin_amdgcn_mfma_f32_16x16x32_bf16(bA[1][s], af, a1, 0, 0, 0);
    }
    {
      f32x4 g = (lm < 8) ? a0 : a1;   // reg0 = gi_r+gh_r (summed by MFMA)
      float r = sigf(g[0] + b0r);
      float z = sigf(g[1] + b0z);
      float nn = tanhfast(g[2] + bi0n + r * (g[3] + bh0n));
      h0 = (1.f - z) * nn + z * h0;
      hb0 = f2b(h0);
      stC[stoff(b, ch)] = hb0;
      stC[stoff(8 + b, ch)] = hb0;
    }
    __syncthreads();

    // ---- R2: flush h0(d)->stA; MFMA; L1 cell + x-store + dense2 partial
    stA[stoff(b, 64 + ch)] = hb0;
    stA[stoff(8 + b, 64 + ch)] = hb0;
    f32x4 c0 = {0.f, 0.f, 0.f, 0.f}, c1 = {0.f, 0.f, 0.f, 0.f};
#pragma unroll
    for (int s = 0; s < 4; ++s) {
      bf16x8 cf = *(const bf16x8*)&stC[((s * 4 + lg) * 17 + lm) * 8];
      c0 = __builtin_amdgcn_mfma_f32_16x16x32_bf16(bC[0][s], cf, c0, 0, 0, 0);
      c1 = __builtin_amdgcn_mfma_f32_16x16x32_bf16(bC[1][s], cf, c1, 0, 0, 0);
    }
    {
      f32x4 g = (lm < 8) ? c0 : c1;
      float r = sigf(g[0] + b1r);
      float z = sigf(g[1] + b1z);
      float nn = tanhfast(g[2] + bi1n + r * (g[3] + bh1n));
      h1 = (1.f - z) * nn + z * h1;
      hb1 = f2b(h1);                  // stC k>=64 DEFERRED to next R1
      stA[stoff(b, ch)] = hb1;        // x(d+1) (R1 reads after barrier)
      stA[stoff(8 + b, ch)] = hb1;
      float p0 = h1 * w2a, p1 = h1 * w2b;   // dense2 partials (this lane's ch)
      p0 += __shfl_xor(p0, 8);  p1 += __shfl_xor(p1, 8);    // mirror halves
      p0 += __shfl_xor(p0, 16); p1 += __shfl_xor(p1, 16);   // quad groups
      p0 += __shfl_xor(p0, 32); p1 += __shfl_xor(p1, 32);
      if (l < 8) {                    // lane l == b, lg=0, mirror=0
        red[wid * 16 + b * 2 + 0] = p0;
        red[wid * 16 + b * 2 + 1] = p1;
      }
    }
    __syncthreads();
  }

  // ---- final output flush (d = 34)
  if (wid == 0 && l < 16) {
    int bb = l >> 1, o = l & 1;
    float s = 0.f;
#pragma unroll
    for (int w = 0; w < NW; ++w) s += red[w * 16 + bb * 2 + o];
    out[((size_t)(bgb + bb) * DECS + (DECS - 1)) * 2 + o] = s + (o ? d2b1 : d2b0);
  }
}

extern "C" void kernel_launch(void* const* d_in, const int* in_sizes, int n_in,
                              void* d_out, int out_size, void* d_ws, size_t ws_size,
                              hipStream_t stream) {
  const float* pulse = (const float*)d_in[0];
  const float* d1w   = (const float*)d_in[1];
  const float* d1b   = (const float*)d_in[2];
  const float* d2w   = (const float*)d_in[3];
  const float* d2b   = (const float*)d_in[4];
  const float* Wih   = (const float*)d_in[5];
  const float* Whh   = (const float*)d_in[6];
  const float* bih   = (const float*)d_in[7];
  const float* bhh   = (const float*)d_in[8];
  const float* emb   = (const float*)d_in[9];
  float* out = (float*)d_out;

  int B = in_sizes[0] / (SEQ * 2);   // 2048
  gru_lane<<<B / BT, NTH, 0, stream>>>(pulse, d1w, d1b, d2w, d2b,
                                       Wih, Whh, bih, bhh, emb, out);
}